// Round 3
// baseline (2747.096 us; speedup 1.0000x reference)
//
#include <hip/hip_runtime.h>

typedef _Float16 f16_t;
typedef _Float16 f16x8 __attribute__((ext_vector_type(8)));
typedef float floatx4 __attribute__((ext_vector_type(4)));

#define GLDS16(gptr, lptr) __builtin_amdgcn_global_load_lds( \
    (const __attribute__((address_space(1))) void*)(gptr),   \
    (__attribute__((address_space(3))) void*)(lptr), 16, 0, 0)

__device__ __forceinline__ float sigmoidf_fast(float x) {
    return 1.f / (1.f + __expf(-x));    // x<<0: exp->inf -> 0 ; x>>0 -> 1
}
__device__ __forceinline__ float tanhf_fast(float x) {
    float e = __expf(2.f * x);          // inf-safe: x>>0 -> 1, x<<0 -> -1
    return 1.f - 2.f / (e + 1.f);
}

// ---------------------------------------------------------------------------
// fp32 -> fp16 conversion, 8 elements/thread, n divisible by 8
// ---------------------------------------------------------------------------
__global__ __launch_bounds__(256)
void cvt_f32_f16(const float* __restrict__ in, f16_t* __restrict__ out, long n)
{
    long i = ((long)blockIdx.x * 256 + threadIdx.x) * 8;
    if (i >= n) return;
    floatx4 a = *(const floatx4*)(in + i);
    floatx4 b = *(const floatx4*)(in + i + 4);
    f16x8 o;
    o[0] = (f16_t)a[0]; o[1] = (f16_t)a[1]; o[2] = (f16_t)a[2]; o[3] = (f16_t)a[3];
    o[4] = (f16_t)b[0]; o[5] = (f16_t)b[1]; o[6] = (f16_t)b[2]; o[7] = (f16_t)b[3];
    *(f16x8*)(out + i) = o;
}

// ---------------------------------------------------------------------------
// gi = encoded @ w_ih^T + b_ih   (M=8192, N=6144, K=2048), fp16 in, fp16 out
// m97 structure: 128x128 tile, BK=32, 4 waves each 64x64 (4x4 MFMA 16x16x32)
// ---------------------------------------------------------------------------
__global__ __launch_bounds__(256, 2)
void gemm_gi(const f16_t* __restrict__ A,   // 8192 x 2048, row-major (K inner)
             const f16_t* __restrict__ W,   // 6144 x 2048, row-major (K inner)
             const float* __restrict__ bias,// 6144 fp32
             f16_t* __restrict__ C)         // 8192 x 6144 fp16
{
    const int K = 2048, NOUT = 6144;
    __shared__ __align__(16) f16_t As[128 * 32];
    __shared__ __align__(16) f16_t Ws[128 * 32];
    const int tid  = threadIdx.x;
    const int lane = tid & 63;
    const int wave = tid >> 6;
    const int m0 = blockIdx.x * 128;
    const int n0 = blockIdx.y * 128;
    const int wm = (wave >> 1) * 64;
    const int wn = (wave & 1) * 64;

    floatx4 acc[4][4] = {};

    const int srow = lane >> 2;        // staging row-within-chunk
    const int skc  = (lane & 3) * 8;   // staging k offset (elements)

    for (int k0 = 0; k0 < K; k0 += 32) {
        #pragma unroll
        for (int j = 0; j < 2; ++j) {
            int c = j * 4 + wave;
            int row = c * 16 + srow;
            GLDS16(A + (size_t)(m0 + row) * K + k0 + skc, As + c * 512);
        }
        #pragma unroll
        for (int j = 0; j < 2; ++j) {
            int c = j * 4 + wave;
            int row = c * 16 + srow;
            GLDS16(W + (size_t)(n0 + row) * K + k0 + skc, Ws + c * 512);
        }
        __syncthreads();   // drains vmcnt for global_load_lds

        const int fr = lane & 15;
        const int fk = (lane >> 4) * 8;
        f16x8 a_frag[4], b_frag[4];
        #pragma unroll
        for (int t = 0; t < 4; ++t)
            a_frag[t] = *(const f16x8*)(As + (wm + t * 16 + fr) * 32 + fk);
        #pragma unroll
        for (int t = 0; t < 4; ++t)
            b_frag[t] = *(const f16x8*)(Ws + (wn + t * 16 + fr) * 32 + fk);
        #pragma unroll
        for (int tm = 0; tm < 4; ++tm)
            #pragma unroll
            for (int tn = 0; tn < 4; ++tn)
                acc[tm][tn] = __builtin_amdgcn_mfma_f32_16x16x32_f16(
                    a_frag[tm], b_frag[tn], acc[tm][tn], 0, 0, 0);
        __syncthreads();
    }

    // epilogue: D[row=(lane>>4)*4+r][col=lane&15]
    const int col = lane & 15;
    const int rq  = (lane >> 4) * 4;
    #pragma unroll
    for (int tm = 0; tm < 4; ++tm) {
        #pragma unroll
        for (int tn = 0; tn < 4; ++tn) {
            int n = n0 + wn + tn * 16 + col;
            float b = bias[n];
            #pragma unroll
            for (int r = 0; r < 4; ++r) {
                int m = m0 + wm + tm * 16 + rq + r;
                C[(size_t)m * NOUT + n] = (f16_t)(acc[tm][tn][r] + b);
            }
        }
    }
}

// ---------------------------------------------------------------------------
// Iteration 1 (h0 = 0): gh = b_hh only, pure elementwise
// ---------------------------------------------------------------------------
__global__ __launch_bounds__(256)
void gru_init(const f16_t* __restrict__ gi,  // 8192 x 6144 fp16
              const float* __restrict__ bhh, // 6144 fp32
              f16_t* __restrict__ h16)
{
    const int H = 2048;
    int idx = blockIdx.x * 256 + threadIdx.x;   // over 8192*2048
    int m = idx >> 11;
    int n = idx & 2047;
    size_t g = (size_t)m * 6144 + n;
    float gr = (float)gi[g]         + bhh[n];
    float gz = (float)gi[g + H]     + bhh[H + n];
    float gn = (float)gi[g + 2 * H];
    float bn = bhh[2 * H + n];
    float r = sigmoidf_fast(gr);
    float z = sigmoidf_fast(gz);
    float nn = tanhf_fast(gn + r * bn);
    float h = (1.f - z) * nn;
    h16[idx] = (f16_t)h;
}

// ---------------------------------------------------------------------------
// Fused gh-GEMM (3 gates) + GRU elementwise update.
// Tile: BM=128 rows, BN=64 h-columns; 3 gate accumulators per block.
// 4 waves in 2x2: each wave 64x32 per gate -> acc[3][4][2] float4.
// h state lives in fp16 ping-pong; |h|<=1 so abs err <= 5e-4.
// ---------------------------------------------------------------------------
__global__ __launch_bounds__(256, 2)
void gru_step(const f16_t* __restrict__ Wh,   // 6144 x 2048 (w_hh, K inner)
              const float* __restrict__ bhh,  // 6144 fp32
              const f16_t* __restrict__ gi,   // 8192 x 6144 fp16
              const f16_t* __restrict__ hin,  // 8192 x 2048 fp16 (GEMM input + h_old)
              f16_t* __restrict__ hout,       // 8192 x 2048 fp16 out
              float* __restrict__ out32)      // nullable: fp32 final output
{
    const int K = 2048, H = 2048;
    __shared__ __align__(16) f16_t As[128 * 32];      // h tile         (8 KiB)
    __shared__ __align__(16) f16_t Ws[3 * 64 * 32];   // 3 gate W tiles (12 KiB)
    const int tid  = threadIdx.x;
    const int lane = tid & 63;
    const int wave = tid >> 6;
    const int m0 = blockIdx.x * 128;
    const int n0 = blockIdx.y * 64;
    const int wm = (wave >> 1) * 64;
    const int wn = (wave & 1) * 32;

    floatx4 acc[3][4][2] = {};

    const int srow = lane >> 2;
    const int skc  = (lane & 3) * 8;

    for (int k0 = 0; k0 < K; k0 += 32) {
        // stage A (h): 8 chunks, 2 per wave
        #pragma unroll
        for (int j = 0; j < 2; ++j) {
            int c = j * 4 + wave;
            int row = c * 16 + srow;
            GLDS16(hin + (size_t)(m0 + row) * K + k0 + skc, As + c * 512);
        }
        // stage W: 12 chunks (3 gates x 4), 3 per wave
        #pragma unroll
        for (int j = 0; j < 3; ++j) {
            int c = j * 4 + wave;        // 0..11
            int g = c >> 2;              // gate
            int ci = c & 3;              // chunk within gate
            int row = ci * 16 + srow;
            GLDS16(Wh + (size_t)(g * H + n0 + row) * K + k0 + skc,
                   Ws + c * 512);
        }
        __syncthreads();

        const int fr = lane & 15;
        const int fk = (lane >> 4) * 8;
        f16x8 a_frag[4];
        #pragma unroll
        for (int t = 0; t < 4; ++t)
            a_frag[t] = *(const f16x8*)(As + (wm + t * 16 + fr) * 32 + fk);
        #pragma unroll
        for (int g = 0; g < 3; ++g) {
            #pragma unroll
            for (int tn = 0; tn < 2; ++tn) {
                f16x8 b_frag = *(const f16x8*)(Ws + g * 2048 +
                                               (wn + tn * 16 + fr) * 32 + fk);
                #pragma unroll
                for (int tm = 0; tm < 4; ++tm)
                    acc[g][tm][tn] = __builtin_amdgcn_mfma_f32_16x16x32_f16(
                        a_frag[tm], b_frag, acc[g][tm][tn], 0, 0, 0);
            }
        }
        __syncthreads();
    }

    // epilogue: GRU update
    const int col = lane & 15;
    const int rq  = (lane >> 4) * 4;
    #pragma unroll
    for (int tm = 0; tm < 4; ++tm) {
        #pragma unroll
        for (int tn = 0; tn < 2; ++tn) {
            int n = n0 + wn + tn * 16 + col;
            float br = bhh[n];
            float bz = bhh[H + n];
            float bn = bhh[2 * H + n];
            #pragma unroll
            for (int r = 0; r < 4; ++r) {
                int m = m0 + wm + tm * 16 + rq + r;
                size_t gbase = (size_t)m * 6144 + n;
                float ghr = acc[0][tm][tn][r] + br;
                float ghz = acc[1][tm][tn][r] + bz;
                float ghn = acc[2][tm][tn][r] + bn;
                float rr = sigmoidf_fast((float)gi[gbase] + ghr);
                float zz = sigmoidf_fast((float)gi[gbase + H] + ghz);
                float nn = tanhf_fast((float)gi[gbase + 2 * H] + rr * ghn);
                size_t hidx = (size_t)m * H + n;
                float hold = (float)hin[hidx];
                float hnew = (1.f - zz) * nn + zz * hold;
                hout[hidx] = (f16_t)hnew;
                if (out32) out32[hidx] = hnew;
            }
        }
    }
}

extern "C" void kernel_launch(void* const* d_in, const int* in_sizes, int n_in,
                              void* d_out, int out_size, void* d_ws, size_t ws_size,
                              hipStream_t stream) {
    const float* x    = (const float*)d_in[0];  // encoded 8192x2048 fp32
    const float* w_ih = (const float*)d_in[1];  // 6144x2048 fp32
    const float* w_hh = (const float*)d_in[2];  // 6144x2048 fp32
    const float* b_ih = (const float*)d_in[3];  // 6144 fp32
    const float* b_hh = (const float*)d_in[4];  // 6144 fp32
    float* out = (float*)d_out;                 // 8192x2048 fp32

    // workspace layout (bytes), total = 240 MiB:
    //   xh    : 16777216 f16 =  33554432
    //   wih_h : 12582912 f16 =  25165824
    //   whh_h : 12582912 f16 =  25165824
    //   gi    : 50331648 f16 = 100663296
    //   h16a/b: 16777216 f16 =  33554432 each
    char* ws = (char*)d_ws;
    f16_t* xh    = (f16_t*)(ws);
    f16_t* wih_h = (f16_t*)(ws + 33554432);
    f16_t* whh_h = (f16_t*)(ws + 33554432 + 25165824);
    f16_t* gi    = (f16_t*)(ws + 33554432 + 2 * 25165824);
    f16_t* h16a  = (f16_t*)(ws + 33554432 + 2 * 25165824 + 100663296);
    f16_t* h16b  = (f16_t*)(ws + 33554432 + 2 * 25165824 + 100663296 + 33554432);

    // 0) convert fp32 inputs to fp16
    cvt_f32_f16<<<dim3(8192), 256, 0, stream>>>(x, xh, 16777216L);
    cvt_f32_f16<<<dim3(6144), 256, 0, stream>>>(w_ih, wih_h, 12582912L);
    cvt_f32_f16<<<dim3(6144), 256, 0, stream>>>(w_hh, whh_h, 12582912L);

    // 1) gi = x @ w_ih^T + b_ih
    gemm_gi<<<dim3(64, 48), 256, 0, stream>>>(xh, wih_h, b_ih, gi);

    // 2) iteration 1 (h0 = 0)
    gru_init<<<dim3(65536), 256, 0, stream>>>(gi, b_hh, h16a);

    // 3) iterations 2..10: fused gh GEMM + update, ping-pong fp16 h
    f16_t* hin = h16a; f16_t* hout = h16b;
    for (int it = 2; it <= 10; ++it) {
        float* o32 = (it == 10) ? out : nullptr;
        gru_step<<<dim3(64, 32), 256, 0, stream>>>(whh_h, b_hh, gi,
                                                   hin, hout, o32);
        f16_t* t = hin; hin = hout; hout = t;
    }
}

// Round 4
// 2676.304 us; speedup vs baseline: 1.0265x; 1.0265x over previous
//
#include <hip/hip_runtime.h>

typedef _Float16 f16_t;
typedef _Float16 f16x4 __attribute__((ext_vector_type(4)));
typedef _Float16 f16x8 __attribute__((ext_vector_type(8)));
typedef float floatx4 __attribute__((ext_vector_type(4)));

#define GLDS16(gptr, lptr) __builtin_amdgcn_global_load_lds( \
    (const __attribute__((address_space(1))) void*)(gptr),   \
    (__attribute__((address_space(3))) void*)(lptr), 16, 0, 0)

__device__ __forceinline__ float sigmoidf_fast(float x) {
    return 1.f / (1.f + __expf(-x));
}
__device__ __forceinline__ float tanhf_fast(float x) {
    float e = __expf(2.f * x);
    return 1.f - 2.f / (e + 1.f);
}

// gi fragment layout: off = ((g*512 + tM)*128 + tN)*256 + lane*4 + r   (f16)
#define GATE_STRIDE 16777216L   // 512*128*256

// ---------------------------------------------------------------------------
__global__ __launch_bounds__(256)
void cvt_f32_f16(const float* __restrict__ in, f16_t* __restrict__ out, long n)
{
    long i = ((long)blockIdx.x * 256 + threadIdx.x) * 8;
    if (i >= n) return;
    floatx4 a = *(const floatx4*)(in + i);
    floatx4 b = *(const floatx4*)(in + i + 4);
    f16x8 o;
    o[0] = (f16_t)a[0]; o[1] = (f16_t)a[1]; o[2] = (f16_t)a[2]; o[3] = (f16_t)a[3];
    o[4] = (f16_t)b[0]; o[5] = (f16_t)b[1]; o[6] = (f16_t)b[2]; o[7] = (f16_t)b[3];
    *(f16x8*)(out + i) = o;
}

// ---------------------------------------------------------------------------
// gi = encoded @ w_ih^T + b_ih, output in fragment-tiled layout.
// XOR-swizzled LDS: chunk slot kc holds global chunk kc ^ ((row>>1)&3).
// ---------------------------------------------------------------------------
__global__ __launch_bounds__(256, 2)
void gemm_gi(const f16_t* __restrict__ A,   // 8192 x 2048 row-major
             const f16_t* __restrict__ W,   // 6144 x 2048 row-major
             const float* __restrict__ bias,// 6144 fp32
             f16_t* __restrict__ giF)       // fragment-tiled
{
    const int K = 2048;
    __shared__ __align__(16) f16_t As[128 * 32];
    __shared__ __align__(16) f16_t Ws[128 * 32];
    const int tid  = threadIdx.x;
    const int lane = tid & 63;
    const int wave = tid >> 6;
    const int m0 = blockIdx.x * 128;
    const int n0 = blockIdx.y * 128;
    const int wm = (wave >> 1) * 64;
    const int wn = (wave & 1) * 64;

    floatx4 acc[4][4] = {};

    const int srow = lane >> 2;
    const int skc  = (((lane & 3) ^ ((srow >> 1) & 3))) * 8;  // swizzled

    const int fr = lane & 15;
    const int jq = lane >> 4;
    const int jsw = (jq ^ ((fr >> 1) & 3)) * 8;               // swizzled read

    for (int k0 = 0; k0 < K; k0 += 32) {
        #pragma unroll
        for (int j = 0; j < 2; ++j) {
            int c = j * 4 + wave;
            int row = c * 16 + srow;
            GLDS16(A + (size_t)(m0 + row) * K + k0 + skc, As + c * 512);
        }
        #pragma unroll
        for (int j = 0; j < 2; ++j) {
            int c = j * 4 + wave;
            int row = c * 16 + srow;
            GLDS16(W + (size_t)(n0 + row) * K + k0 + skc, Ws + c * 512);
        }
        __syncthreads();

        f16x8 a_frag[4], b_frag[4];
        #pragma unroll
        for (int t = 0; t < 4; ++t)
            a_frag[t] = *(const f16x8*)(As + (wm + t * 16 + fr) * 32 + jsw);
        #pragma unroll
        for (int t = 0; t < 4; ++t)
            b_frag[t] = *(const f16x8*)(Ws + (wn + t * 16 + fr) * 32 + jsw);
        #pragma unroll
        for (int tm = 0; tm < 4; ++tm)
            #pragma unroll
            for (int tn = 0; tn < 4; ++tn)
                acc[tm][tn] = __builtin_amdgcn_mfma_f32_16x16x32_f16(
                    a_frag[tm], b_frag[tn], acc[tm][tn], 0, 0, 0);
        __syncthreads();
    }

    // epilogue: write fragment-tiled, 8B/lane coalesced
    const int g   = n0 >> 11;
    const int tNb = ((n0 & 2047) >> 4) + (wn >> 4);
    #pragma unroll
    for (int tm = 0; tm < 4; ++tm) {
        int tM = (m0 + wm + tm * 16) >> 4;
        #pragma unroll
        for (int tn = 0; tn < 4; ++tn) {
            int tN = tNb + tn;
            int n  = n0 + wn + tn * 16 + fr;
            float b = bias[n];
            f16x4 v;
            #pragma unroll
            for (int r = 0; r < 4; ++r) v[r] = (f16_t)(acc[tm][tn][r] + b);
            *(f16x4*)(giF + ((size_t)(g * 512 + tM) * 128 + tN) * 256 + lane * 4) = v;
        }
    }
}

// ---------------------------------------------------------------------------
// Iteration 1 (h0=0): gh = b_hh. Reads fragment-tiled gi, writes row-major h16
// via LDS transpose (conflict-free 72-f16 row stride).
// ---------------------------------------------------------------------------
__global__ __launch_bounds__(256)
void gru_init(const f16_t* __restrict__ giF,
              const float* __restrict__ bhh,
              f16_t* __restrict__ h16)
{
    const int H = 2048;
    __shared__ __align__(16) f16_t hp[128 * 72];
    const int tid  = threadIdx.x;
    const int lane = tid & 63;
    const int wave = tid >> 6;
    const int m0 = blockIdx.x * 128;
    const int n0 = blockIdx.y * 64;
    const int wm = (wave >> 1) * 64;
    const int wn = (wave & 1) * 32;
    const int colL = lane & 15;
    const int rq = (lane >> 4) * 4;

    #pragma unroll
    for (int tm = 0; tm < 4; ++tm) {
        int tM = (m0 + wm + tm * 16) >> 4;
        #pragma unroll
        for (int tn = 0; tn < 2; ++tn) {
            int tN = ((n0 + wn) >> 4) + tn;
            size_t base = ((size_t)tM * 128 + tN) * 256 + lane * 4;
            f16x4 g_r = *(const f16x4*)(giF + base);
            f16x4 g_z = *(const f16x4*)(giF + base + GATE_STRIDE);
            f16x4 g_n = *(const f16x4*)(giF + base + 2 * GATE_STRIDE);
            int n = n0 + wn + tn * 16 + colL;
            float br = bhh[n], bz = bhh[H + n], bn = bhh[2 * H + n];
            #pragma unroll
            for (int r = 0; r < 4; ++r) {
                float rr = sigmoidf_fast((float)g_r[r]);
                float zz = sigmoidf_fast((float)g_z[r]);
                float nn = tanhf_fast((float)g_n[r] + rr * bn);
                // note: gi already includes b_ih only; b_hh for r,z gates:
                // recompute with biases included
                rr = sigmoidf_fast((float)g_r[r] + br);
                zz = sigmoidf_fast((float)g_z[r] + bz);
                float h = (1.f - zz) * nn;
                hp[(wm + tm * 16 + rq + r) * 72 + wn + tn * 16 + colL] = (f16_t)h;
            }
        }
    }
    __syncthreads();
    #pragma unroll
    for (int i = 0; i < 4; ++i) {
        int r2 = i * 32 + (tid >> 3);
        int ch = tid & 7;
        f16x8 v = *(const f16x8*)(hp + r2 * 72 + ch * 8);
        *(f16x8*)(h16 + (size_t)(m0 + r2) * H + n0 + ch * 8) = v;
    }
}

// ---------------------------------------------------------------------------
// Fused gh-GEMM (3 gates) + GRU update. BM=128, BN=64.
// Swizzled LDS, fragment-tiled gi reads, LDS-transposed hout stores.
// ---------------------------------------------------------------------------
__global__ __launch_bounds__(256, 2)
void gru_step(const f16_t* __restrict__ Wh,   // 6144 x 2048 row-major
              const float* __restrict__ bhh,  // 6144 fp32
              const f16_t* __restrict__ giF,  // fragment-tiled
              const f16_t* __restrict__ hin,  // 8192 x 2048 f16 row-major
              f16_t* __restrict__ hout,       // 8192 x 2048 f16 row-major
              float* __restrict__ out32)      // nullable fp32 final out
{
    const int K = 2048, H = 2048;
    __shared__ __align__(16) f16_t smem[128 * 32 + 3 * 64 * 32];  // 20 KiB
    f16_t* As  = smem;
    f16_t* Wsm = smem + 128 * 32;
    const int tid  = threadIdx.x;
    const int lane = tid & 63;
    const int wave = tid >> 6;
    const int m0 = blockIdx.x * 128;
    const int n0 = blockIdx.y * 64;
    const int wm = (wave >> 1) * 64;
    const int wn = (wave & 1) * 32;

    floatx4 acc[3][4][2] = {};

    const int srow = lane >> 2;
    const int skc  = (((lane & 3) ^ ((srow >> 1) & 3))) * 8;
    const int fr = lane & 15;
    const int jq = lane >> 4;
    const int jsw = (jq ^ ((fr >> 1) & 3)) * 8;

    for (int k0 = 0; k0 < K; k0 += 32) {
        #pragma unroll
        for (int j = 0; j < 2; ++j) {
            int c = j * 4 + wave;
            int row = c * 16 + srow;
            GLDS16(hin + (size_t)(m0 + row) * K + k0 + skc, As + c * 512);
        }
        #pragma unroll
        for (int j = 0; j < 3; ++j) {
            int c = j * 4 + wave;
            int g = c >> 2;
            int ci = c & 3;
            int row = ci * 16 + srow;
            GLDS16(Wh + (size_t)(g * H + n0 + row) * K + k0 + skc,
                   Wsm + c * 512);
        }
        __syncthreads();

        f16x8 a_frag[4];
        #pragma unroll
        for (int t = 0; t < 4; ++t)
            a_frag[t] = *(const f16x8*)(As + (wm + t * 16 + fr) * 32 + jsw);
        #pragma unroll
        for (int g = 0; g < 3; ++g) {
            #pragma unroll
            for (int tn = 0; tn < 2; ++tn) {
                f16x8 b_frag = *(const f16x8*)(Wsm + g * 2048 +
                                               (wn + tn * 16 + fr) * 32 + jsw);
                #pragma unroll
                for (int tm = 0; tm < 4; ++tm)
                    acc[g][tm][tn] = __builtin_amdgcn_mfma_f32_16x16x32_f16(
                        a_frag[tm], b_frag, acc[g][tm][tn], 0, 0, 0);
            }
        }
        __syncthreads();
    }

    // epilogue
    const int rq = (lane >> 4) * 4;
    f16x4 hv[4][2];
    #pragma unroll
    for (int tm = 0; tm < 4; ++tm) {
        int tM = (m0 + wm + tm * 16) >> 4;
        #pragma unroll
        for (int tn = 0; tn < 2; ++tn) {
            int tN = ((n0 + wn) >> 4) + tn;
            size_t base = ((size_t)tM * 128 + tN) * 256 + lane * 4;
            f16x4 g_r = *(const f16x4*)(giF + base);
            f16x4 g_z = *(const f16x4*)(giF + base + GATE_STRIDE);
            f16x4 g_n = *(const f16x4*)(giF + base + 2 * GATE_STRIDE);
            int n = n0 + wn + tn * 16 + fr;
            float br = bhh[n], bz = bhh[H + n], bn = bhh[2 * H + n];
            #pragma unroll
            for (int r = 0; r < 4; ++r) {
                int m = m0 + wm + tm * 16 + rq + r;
                float rr = sigmoidf_fast((float)g_r[r] + acc[0][tm][tn][r] + br);
                float zz = sigmoidf_fast((float)g_z[r] + acc[1][tm][tn][r] + bz);
                float nn = tanhf_fast((float)g_n[r] +
                                      rr * (acc[2][tm][tn][r] + bn));
                float hold = (float)hin[(size_t)m * H + n];
                float hnew = (1.f - zz) * nn + zz * hold;
                hv[tm][tn][r] = (f16_t)hnew;
                if (out32) out32[(size_t)m * H + n] = hnew;
            }
        }
    }

    if (!out32) {
        // LDS transpose -> coalesced f16x8 stores
        f16_t* hp = smem;   // reuse (18432 B <= 20480 B)
        #pragma unroll
        for (int tm = 0; tm < 4; ++tm)
            #pragma unroll
            for (int tn = 0; tn < 2; ++tn)
                #pragma unroll
                for (int r = 0; r < 4; ++r)
                    hp[(wm + tm * 16 + rq + r) * 72 + wn + tn * 16 + fr] =
                        hv[tm][tn][r];
        __syncthreads();
        #pragma unroll
        for (int i = 0; i < 4; ++i) {
            int r2 = i * 32 + (tid >> 3);
            int ch = tid & 7;
            f16x8 v = *(const f16x8*)(hp + r2 * 72 + ch * 8);
            *(f16x8*)(hout + (size_t)(m0 + r2) * H + n0 + ch * 8) = v;
        }
    }
}

extern "C" void kernel_launch(void* const* d_in, const int* in_sizes, int n_in,
                              void* d_out, int out_size, void* d_ws, size_t ws_size,
                              hipStream_t stream) {
    const float* x    = (const float*)d_in[0];
    const float* w_ih = (const float*)d_in[1];
    const float* w_hh = (const float*)d_in[2];
    const float* b_ih = (const float*)d_in[3];
    const float* b_hh = (const float*)d_in[4];
    float* out = (float*)d_out;

    char* ws = (char*)d_ws;
    f16_t* xh    = (f16_t*)(ws);
    f16_t* wih_h = (f16_t*)(ws + 33554432);
    f16_t* whh_h = (f16_t*)(ws + 33554432 + 25165824);
    f16_t* gi    = (f16_t*)(ws + 33554432 + 2 * 25165824);
    f16_t* h16a  = (f16_t*)(ws + 33554432 + 2 * 25165824 + 100663296);
    f16_t* h16b  = (f16_t*)(ws + 33554432 + 2 * 25165824 + 100663296 + 33554432);

    cvt_f32_f16<<<dim3(8192), 256, 0, stream>>>(x, xh, 16777216L);
    cvt_f32_f16<<<dim3(6144), 256, 0, stream>>>(w_ih, wih_h, 12582912L);
    cvt_f32_f16<<<dim3(6144), 256, 0, stream>>>(w_hh, whh_h, 12582912L);

    gemm_gi<<<dim3(64, 48), 256, 0, stream>>>(xh, wih_h, b_ih, gi);
    gru_init<<<dim3(64, 32), 256, 0, stream>>>(gi, b_hh, h16a);

    f16_t* hin = h16a; f16_t* hout = h16b;
    for (int it = 2; it <= 10; ++it) {
        float* o32 = (it == 10) ? out : nullptr;
        gru_step<<<dim3(64, 32), 256, 0, stream>>>(whh_h, b_hh, gi,
                                                   hin, hout, o32);
        f16_t* t = hin; hin = hout; hout = t;
    }
}

// Round 5
// 2524.654 us; speedup vs baseline: 1.0881x; 1.0601x over previous
//
#include <hip/hip_runtime.h>

typedef _Float16 f16_t;
typedef _Float16 f16x4 __attribute__((ext_vector_type(4)));
typedef _Float16 f16x8 __attribute__((ext_vector_type(8)));
typedef float floatx4 __attribute__((ext_vector_type(4)));

#define GLDS16(gptr, lptr) __builtin_amdgcn_global_load_lds( \
    (const __attribute__((address_space(1))) void*)(gptr),   \
    (__attribute__((address_space(3))) void*)(lptr), 16, 0, 0)

__device__ __forceinline__ float sigmoidf_fast(float x) {
    return 1.f / (1.f + __expf(-x));
}
__device__ __forceinline__ float tanhf_fast(float x) {
    float e = __expf(2.f * x);
    return 1.f - 2.f / (e + 1.f);
}

// gi fragment layout: off = ((g*512 + tM)*128 + tN)*256 + lane*4 + r   (f16)
#define GATE_STRIDE 16777216L   // 512*128*256

// ---------------------------------------------------------------------------
__global__ __launch_bounds__(256)
void cvt_f32_f16(const float* __restrict__ in, f16_t* __restrict__ out, long n)
{
    long i = ((long)blockIdx.x * 256 + threadIdx.x) * 8;
    if (i >= n) return;
    floatx4 a = *(const floatx4*)(in + i);
    floatx4 b = *(const floatx4*)(in + i + 4);
    f16x8 o;
    o[0] = (f16_t)a[0]; o[1] = (f16_t)a[1]; o[2] = (f16_t)a[2]; o[3] = (f16_t)a[3];
    o[4] = (f16_t)b[0]; o[5] = (f16_t)b[1]; o[6] = (f16_t)b[2]; o[7] = (f16_t)b[3];
    *(f16x8*)(out + i) = o;
}

// ---------------------------------------------------------------------------
// gi = encoded @ w_ih^T + b_ih, fragment-tiled output. (proven R3 version,
// BK=32, 64B-row swizzle)
// ---------------------------------------------------------------------------
__global__ __launch_bounds__(256, 2)
void gemm_gi(const f16_t* __restrict__ A,
             const f16_t* __restrict__ W,
             const float* __restrict__ bias,
             f16_t* __restrict__ giF)
{
    const int K = 2048;
    __shared__ __align__(16) f16_t As[128 * 32];
    __shared__ __align__(16) f16_t Ws[128 * 32];
    const int tid  = threadIdx.x;
    const int lane = tid & 63;
    const int wave = tid >> 6;
    const int m0 = blockIdx.x * 128;
    const int n0 = blockIdx.y * 128;
    const int wm = (wave >> 1) * 64;
    const int wn = (wave & 1) * 64;

    floatx4 acc[4][4] = {};

    const int srow = lane >> 2;
    const int skc  = (((lane & 3) ^ ((srow >> 1) & 3))) * 8;
    const int fr = lane & 15;
    const int jq = lane >> 4;
    const int jsw = (jq ^ ((fr >> 1) & 3)) * 8;

    for (int k0 = 0; k0 < K; k0 += 32) {
        #pragma unroll
        for (int j = 0; j < 2; ++j) {
            int c = j * 4 + wave;
            int row = c * 16 + srow;
            GLDS16(A + (size_t)(m0 + row) * K + k0 + skc, As + c * 512);
        }
        #pragma unroll
        for (int j = 0; j < 2; ++j) {
            int c = j * 4 + wave;
            int row = c * 16 + srow;
            GLDS16(W + (size_t)(n0 + row) * K + k0 + skc, Ws + c * 512);
        }
        __syncthreads();

        f16x8 a_frag[4], b_frag[4];
        #pragma unroll
        for (int t = 0; t < 4; ++t)
            a_frag[t] = *(const f16x8*)(As + (wm + t * 16 + fr) * 32 + jsw);
        #pragma unroll
        for (int t = 0; t < 4; ++t)
            b_frag[t] = *(const f16x8*)(Ws + (wn + t * 16 + fr) * 32 + jsw);
        #pragma unroll
        for (int tm = 0; tm < 4; ++tm)
            #pragma unroll
            for (int tn = 0; tn < 4; ++tn)
                acc[tm][tn] = __builtin_amdgcn_mfma_f32_16x16x32_f16(
                    a_frag[tm], b_frag[tn], acc[tm][tn], 0, 0, 0);
        __syncthreads();
    }

    const int g   = n0 >> 11;
    const int tNb = ((n0 & 2047) >> 4) + (wn >> 4);
    #pragma unroll
    for (int tm = 0; tm < 4; ++tm) {
        int tM = (m0 + wm + tm * 16) >> 4;
        #pragma unroll
        for (int tn = 0; tn < 4; ++tn) {
            int tN = tNb + tn;
            int n  = n0 + wn + tn * 16 + fr;
            float b = bias[n];
            f16x4 v;
            #pragma unroll
            for (int r = 0; r < 4; ++r) v[r] = (f16_t)(acc[tm][tn][r] + b);
            *(f16x4*)(giF + ((size_t)(g * 512 + tM) * 128 + tN) * 256 + lane * 4) = v;
        }
    }
}

// ---------------------------------------------------------------------------
// Iteration 1 (h0=0): gh = b_hh only.
// ---------------------------------------------------------------------------
__global__ __launch_bounds__(256)
void gru_init(const f16_t* __restrict__ giF,
              const float* __restrict__ bhh,
              f16_t* __restrict__ h16)
{
    const int H = 2048;
    __shared__ __align__(16) f16_t hp[128 * 72];
    const int tid  = threadIdx.x;
    const int lane = tid & 63;
    const int wave = tid >> 6;
    const int m0 = blockIdx.x * 128;
    const int n0 = blockIdx.y * 64;
    const int wm = (wave >> 1) * 64;
    const int wn = (wave & 1) * 32;
    const int colL = lane & 15;
    const int rq = (lane >> 4) * 4;

    #pragma unroll
    for (int tm = 0; tm < 4; ++tm) {
        int tM = (m0 + wm + tm * 16) >> 4;
        #pragma unroll
        for (int tn = 0; tn < 2; ++tn) {
            int tN = ((n0 + wn) >> 4) + tn;
            size_t base = ((size_t)tM * 128 + tN) * 256 + lane * 4;
            f16x4 g_r = *(const f16x4*)(giF + base);
            f16x4 g_z = *(const f16x4*)(giF + base + GATE_STRIDE);
            f16x4 g_n = *(const f16x4*)(giF + base + 2 * GATE_STRIDE);
            int n = n0 + wn + tn * 16 + colL;
            float br = bhh[n], bz = bhh[H + n], bn = bhh[2 * H + n];
            #pragma unroll
            for (int r = 0; r < 4; ++r) {
                float rr = sigmoidf_fast((float)g_r[r] + br);
                float zz = sigmoidf_fast((float)g_z[r] + bz);
                float nn = tanhf_fast((float)g_n[r] + rr * bn);
                float h = (1.f - zz) * nn;
                hp[(wm + tm * 16 + rq + r) * 72 + wn + tn * 16 + colL] = (f16_t)h;
            }
        }
    }
    __syncthreads();
    #pragma unroll
    for (int i = 0; i < 4; ++i) {
        int r2 = i * 32 + (tid >> 3);
        int ch = tid & 7;
        f16x8 v = *(const f16x8*)(hp + r2 * 72 + ch * 8);
        *(f16x8*)(h16 + (size_t)(m0 + r2) * H + n0 + ch * 8) = v;
    }
}

// ---------------------------------------------------------------------------
// Fused gh-GEMM (3 gates) + GRU update. BM=128, BN=64, BK=64.
// 128B-row LDS with 8-slot XOR swizzle (slot s of row r holds chunk s^(r&7)).
// hold(h_prev) captured from the As tile at k0 == n0 (no global re-read).
// XCD-swizzled 1D grid: each XCD sees 4 n-tiles (3.1 MB w_hh slice in L2).
// ---------------------------------------------------------------------------
__global__ __launch_bounds__(256, 2)
void gru_step(const f16_t* __restrict__ Wh,
              const float* __restrict__ bhh,
              const f16_t* __restrict__ giF,
              const f16_t* __restrict__ hin,
              f16_t* __restrict__ hout,
              float* __restrict__ out32)
{
    const int K = 2048, H = 2048;
    __shared__ __align__(16) f16_t smem[128 * 64 + 3 * 64 * 64];  // 40 KiB
    f16_t* As  = smem;              // 128 rows x 64
    f16_t* Wsm = smem + 128 * 64;   // 3 gates x 64 rows x 64
    const int tid  = threadIdx.x;
    const int lane = tid & 63;
    const int wave = tid >> 6;

    // XCD-aware decomposition of 2048 blocks
    const int bid   = blockIdx.x;
    const int xcd   = bid & 7;
    const int rblk  = bid >> 3;           // 0..255
    const int m0 = (rblk >> 2) * 128;     // 64 m-tiles
    const int n0 = (xcd * 4 + (rblk & 3)) * 64;   // 32 n-tiles

    const int wm = (wave >> 1) * 64;
    const int wn = (wave & 1) * 32;

    floatx4 acc[3][4][2] = {};

    // staging: 1 KiB chunk = 8 rows x 64 f16; lane -> row lane>>3, slot lane&7
    const int srow8 = lane >> 3;
    const int sgk   = ((lane & 7) ^ srow8) * 8;   // swizzled global chunk
    const int fr = lane & 15;
    const int jq = lane >> 4;                     // 0..3
    const int rq = (lane >> 4) * 4;

    f16x4 hold16[4][2];   // h_prev captured from LDS

    for (int k0 = 0; k0 < K; k0 += 64) {
        // A: 16 chunks, 4/wave
        #pragma unroll
        for (int j = 0; j < 4; ++j) {
            int c = j * 4 + wave;
            int row = c * 8 + srow8;
            GLDS16(hin + (size_t)(m0 + row) * K + k0 + sgk, As + c * 512);
        }
        // W: 24 chunks (3 gates x 8), 6/wave
        #pragma unroll
        for (int j = 0; j < 6; ++j) {
            int c = j * 4 + wave;
            int g = c >> 3;
            int cw = c & 7;
            int row = cw * 8 + srow8;
            GLDS16(Wh + (size_t)(g * H + n0 + row) * K + k0 + sgk,
                   Wsm + c * 512);
        }
        __syncthreads();

        if (k0 == n0) {   // wave-uniform, once: capture h_prev from As
            #pragma unroll
            for (int tm = 0; tm < 4; ++tm) {
                #pragma unroll
                for (int tn = 0; tn < 2; ++tn) {
                    #pragma unroll
                    for (int r = 0; r < 4; ++r) {
                        int row_a = wm + tm * 16 + rq + r;
                        int kloc  = wn + tn * 16 + fr;
                        int slot  = (kloc >> 3) ^ (row_a & 7);
                        hold16[tm][tn][r] =
                            As[row_a * 64 + slot * 8 + (kloc & 7)];
                    }
                }
            }
        }

        #pragma unroll
        for (int ksub = 0; ksub < 2; ++ksub) {
            f16x8 a_frag[4];
            #pragma unroll
            for (int t = 0; t < 4; ++t) {
                int row = wm + t * 16 + fr;
                int slot = (ksub * 4 + jq) ^ (row & 7);
                a_frag[t] = *(const f16x8*)(As + row * 64 + slot * 8);
            }
            #pragma unroll
            for (int g = 0; g < 3; ++g) {
                #pragma unroll
                for (int tn = 0; tn < 2; ++tn) {
                    int row_w = wn + tn * 16 + fr;
                    int slot = (ksub * 4 + jq) ^ (row_w & 7);
                    f16x8 b_frag = *(const f16x8*)(Wsm + g * 4096 +
                                                   row_w * 64 + slot * 8);
                    #pragma unroll
                    for (int tm = 0; tm < 4; ++tm)
                        acc[g][tm][tn] = __builtin_amdgcn_mfma_f32_16x16x32_f16(
                            a_frag[tm], b_frag, acc[g][tm][tn], 0, 0, 0);
                }
            }
        }
        __syncthreads();
    }

    // epilogue
    f16x4 hv[4][2];
    #pragma unroll
    for (int tm = 0; tm < 4; ++tm) {
        int tM = (m0 + wm + tm * 16) >> 4;
        #pragma unroll
        for (int tn = 0; tn < 2; ++tn) {
            int tN = ((n0 + wn) >> 4) + tn;
            size_t base = ((size_t)tM * 128 + tN) * 256 + lane * 4;
            f16x4 g_r = *(const f16x4*)(giF + base);
            f16x4 g_z = *(const f16x4*)(giF + base + GATE_STRIDE);
            f16x4 g_n = *(const f16x4*)(giF + base + 2 * GATE_STRIDE);
            int n = n0 + wn + tn * 16 + fr;
            float br = bhh[n], bz = bhh[H + n], bn = bhh[2 * H + n];
            #pragma unroll
            for (int r = 0; r < 4; ++r) {
                int m = m0 + wm + tm * 16 + rq + r;
                float rr = sigmoidf_fast((float)g_r[r] + acc[0][tm][tn][r] + br);
                float zz = sigmoidf_fast((float)g_z[r] + acc[1][tm][tn][r] + bz);
                float nn = tanhf_fast((float)g_n[r] +
                                      rr * (acc[2][tm][tn][r] + bn));
                float hold = (float)hold16[tm][tn][r];
                float hnew = (1.f - zz) * nn + zz * hold;
                hv[tm][tn][r] = (f16_t)hnew;
                if (out32) out32[(size_t)m * H + n] = hnew;
            }
        }
    }

    if (!out32) {
        f16_t* hp = smem;   // reuse (18 KiB <= 40 KiB); guarded by last barrier
        #pragma unroll
        for (int tm = 0; tm < 4; ++tm)
            #pragma unroll
            for (int tn = 0; tn < 2; ++tn)
                #pragma unroll
                for (int r = 0; r < 4; ++r)
                    hp[(wm + tm * 16 + rq + r) * 72 + wn + tn * 16 + fr] =
                        hv[tm][tn][r];
        __syncthreads();
        #pragma unroll
        for (int i = 0; i < 4; ++i) {
            int r2 = i * 32 + (tid >> 3);
            int ch = tid & 7;
            f16x8 v = *(const f16x8*)(hp + r2 * 72 + ch * 8);
            *(f16x8*)(hout + (size_t)(m0 + r2) * H + n0 + ch * 8) = v;
        }
    }
}

extern "C" void kernel_launch(void* const* d_in, const int* in_sizes, int n_in,
                              void* d_out, int out_size, void* d_ws, size_t ws_size,
                              hipStream_t stream) {
    const float* x    = (const float*)d_in[0];
    const float* w_ih = (const float*)d_in[1];
    const float* w_hh = (const float*)d_in[2];
    const float* b_ih = (const float*)d_in[3];
    const float* b_hh = (const float*)d_in[4];
    float* out = (float*)d_out;

    char* ws = (char*)d_ws;
    f16_t* xh    = (f16_t*)(ws);
    f16_t* wih_h = (f16_t*)(ws + 33554432);
    f16_t* whh_h = (f16_t*)(ws + 33554432 + 25165824);
    f16_t* gi    = (f16_t*)(ws + 33554432 + 2 * 25165824);
    f16_t* h16a  = (f16_t*)(ws + 33554432 + 2 * 25165824 + 100663296);
    f16_t* h16b  = (f16_t*)(ws + 33554432 + 2 * 25165824 + 100663296 + 33554432);

    cvt_f32_f16<<<dim3(8192), 256, 0, stream>>>(x, xh, 16777216L);
    cvt_f32_f16<<<dim3(6144), 256, 0, stream>>>(w_ih, wih_h, 12582912L);
    cvt_f32_f16<<<dim3(6144), 256, 0, stream>>>(w_hh, whh_h, 12582912L);

    gemm_gi<<<dim3(64, 48), 256, 0, stream>>>(xh, wih_h, b_ih, gi);
    gru_init<<<dim3(64, 32), 256, 0, stream>>>(gi, b_hh, h16a);

    f16_t* hin = h16a; f16_t* hout = h16b;
    for (int it = 2; it <= 10; ++it) {
        float* o32 = (it == 10) ? out : nullptr;
        gru_step<<<dim3(2048), 256, 0, stream>>>(whh_h, b_hh, gi,
                                                 hin, hout, o32);
        f16_t* t = hin; hin = hout; hout = t;
    }
}